// Round 2
// baseline (281.649 us; speedup 1.0000x reference)
//
#include <hip/hip_runtime.h>

#define IMG     256
#define NIMG    384                    // B*C = 128*3
#define STEPS   64
#define ROWS_PW 8                      // rows per wave (R8: reverted 16 -> 8;
                                       // 16 crossed the 128-VGPR occupancy cliff, +6us)
#define WAVES   4
#define ROWS_PB (ROWS_PW * WAVES)      // 32 rows per block
#define BANDS   (IMG / ROWS_PB)        // 8 blocks per image -> 3072 blocks
#define NROWS   (ROWS_PW + 2)          // rows held in registers (with halo)
#define INFV    1e30f
#define POISON  0xAAAAAAAAu            // harness 0xAA byte-poison of d_ws

// bin = clip(ceil((v-0.02)/RES), 0, 63); fused form ceil(v*65.625 - 1.3125).
// Differs from the reference's f32 divide only on ~ULP bin-boundary values;
// absmax tolerance absorbs that.
__device__ __forceinline__ int bin_of(float v) {
    int t = (int)ceilf(__builtin_fmaf(v, 65.625f, -1.3125f));
    t = t < 0 ? 0 : t;
    return t > 63 ? 63 : t;
}

// Max-vertex attribution: each cell (vertex/edge/square) is attributed to its
// (value, index)-max corner; all cells owned by a pixel share its filtration
// -> one integer LDS-histogram add per pixel.
// R5 lesson kept: ALL row loads issued back-to-back (single vmcnt drain per
// wave). R6 lessons kept: inlined per-row halo shuffles; every cell-pair
// compare computed ONCE and reused complemented (a<=b == !(b<a)).
// R8 (new): single-kernel design. cumsum is linear, so each block scans its
// own 64-bin histogram in-wave and device-scope-atomicAdds the cumsum into a
// per-image accumulator; a ticket atomicAdd elects the LAST band block of
// each image to finalize (subtract poison base, write f32 out, restore
// poison). Eliminates the ecc_scan launch + gap + 768 KiB hist round-trip.
// Poison-robustness: ticket check is mod-BANDS (works whether or not ws is
// re-poisoned between iterations); finalizer restores acc/ticket to POISON,
// so state is correct for the next launch either way.
__global__ __launch_bounds__(256) void ecc_fused(const float* __restrict__ x,
                                                 unsigned* __restrict__ acc,
                                                 unsigned* __restrict__ ticket,
                                                 float* __restrict__ out) {
    const int img  = blockIdx.x / BANDS;
    const int band = blockIdx.x % BANDS;
    const int lane = threadIdx.x & 63;
    const int wave = threadIdx.x >> 6;
    const int col0 = lane * 4;
    const int r0   = band * ROWS_PB + wave * ROWS_PW;

    __shared__ int lh[WAVES][STEPS];           // per-wave sub-histograms
    ((int*)lh)[threadIdx.x] = 0;               // 4*64 == 256
    __syncthreads();

    const float* base = x + (size_t)img * (IMG * IMG);

    // Stage 1: all row loads back-to-back (wave's 64 lanes x 4 cols = one
    // full 256-wide row -> exactly 1 VMEM instruction per row).
    float4 q[NROWS];
#pragma unroll
    for (int k = 0; k < NROWS; ++k) {
        int r = r0 - 1 + k;                    // wave-uniform bounds test
        if ((unsigned)r < IMG) q[k] = *(const float4*)(base + r * IMG + col0);
        else                   q[k] = make_float4(INFV, INFV, INFV, INFV);
    }

    auto halo = [&](int k, float& l, float& r) {
        float lv = __shfl_up(q[k].w, 1, 64);   // lane-1's last element
        float rv = __shfl_down(q[k].x, 1, 64); // lane+1's first element
        l = (lane == 0)  ? INFV : lv;          // lane 0 = image col 0
        r = (lane == 63) ? INFV : rv;          // lane 63 ends at col 255
    };

    // Carried up-row flags (window cols 1..4): pU[i]=(u[i]<=c[i]),
    // pUR[i]=(u[i+1]<=c[i]), pUL[i]=(u[i-1]<=c[i]).
    bool pU[5], pUR[5], pUL[5];
    float chl, chr;                            // halos of current c row
    {
        float uhl, uhr;
        halo(0, uhl, uhr);
        halo(1, chl, chr);
        float u[6] = {uhl, q[0].x, q[0].y, q[0].z, q[0].w, uhr};
        float c[6] = {chl, q[1].x, q[1].y, q[1].z, q[1].w, chr};
#pragma unroll
        for (int i = 1; i <= 4; ++i) {
            pU[i]  = (u[i]     <= c[i]);
            pUR[i] = (u[i + 1] <= c[i]);
            pUL[i] = (u[i - 1] <= c[i]);
        }
    }

#pragma unroll
    for (int k = 1; k <= ROWS_PW; ++k) {
        float dhl, dhr;
        halo(k + 1, dhl, dhr);
        float c[6] = {chl, q[k].x,     q[k].y,     q[k].z,     q[k].w,     chr};
        float d[6] = {dhl, q[k + 1].x, q[k + 1].y, q[k + 1].z, q[k + 1].w, dhr};

        bool eD[5], dDR[5], dDL[5], eR[5];
#pragma unroll
        for (int i = 1; i <= 4; ++i) {
            eD[i]  = (d[i]     < c[i]);        // p owns down edge
            dDR[i] = (d[i + 1] < c[i]);        // down-right diagonal compare
            dDL[i] = (d[i - 1] < c[i]);        // down-left  diagonal compare
            eR[i]  = (c[i + 1] < c[i]);        // p owns right edge
        }
        bool dDRm = (d[1] < c[0]);             // serves next row's pUL[1]
        bool dDLp = (d[4] < c[5]);             // serves next row's pUR[4]
        bool oLn  = (c[0] <= c[1]);            // oL for i=1

#pragma unroll
        for (int i = 1; i <= 4; ++i) {
            float cv = c[i];
            bool oR = eR[i], oL = oLn, oD = eD[i], oU = pU[i];
            bool sDR = oR & oD & dDR[i];
            bool sDL = oL & oD & dDL[i];
            bool sUR = oU & oR & pUR[i];
            bool sUL = oU & oL & pUL[i];
            int contrib = 1 - ((int)oR + (int)oL + (int)oD + (int)oU)
                            + ((int)sDR + (int)sDL + (int)sUR + (int)sUL);
            if (cv <= 0.98f && contrib)        // reference T_MAX mask
                atomicAdd(&lh[wave][bin_of(cv)], contrib);
            oLn = !eR[i];                      // oL(i+1) = !(c[i+1] < c[i])
        }

        // rotate: current down-compares become next row's up-flags (negated)
#pragma unroll
        for (int i = 1; i <= 4; ++i) pU[i] = !eD[i];
        pUR[1] = !dDL[2]; pUR[2] = !dDL[3]; pUR[3] = !dDL[4]; pUR[4] = !dDLp;
        pUL[1] = !dDRm;   pUL[2] = !dDR[1]; pUL[3] = !dDR[2]; pUL[4] = !dDR[3];
        chl = dhl; chr = dhr;
    }

    // ---- fused epilogue: per-block cumsum -> device-scope accumulate ----
    __syncthreads();                           // lh final
    const int t = threadIdx.x;
    if (t < STEPS) {
        int v = lh[0][t] + lh[1][t] + lh[2][t] + lh[3][t];
#pragma unroll
        for (int s = 1; s < 64; s <<= 1) {     // inclusive in-wave scan
            int y = __shfl_up(v, s, 64);
            if (t >= s) v += y;
        }
        __hip_atomic_fetch_add(&acc[img * STEPS + t], (unsigned)v,
                               __ATOMIC_RELAXED, __HIP_MEMORY_SCOPE_AGENT);
    }
    __syncthreads();                           // all 64 acc-adds completed

    __shared__ int lastflag;
    if (t == 0) {
        unsigned old = __hip_atomic_fetch_add(&ticket[img], 1u,
                                              __ATOMIC_ACQ_REL,
                                              __HIP_MEMORY_SCOPE_AGENT);
        // exactly BANDS arrivals per image per launch; mod-BANDS is robust
        // to poison-base and to missing re-poison between iterations
        lastflag = (((old - POISON) & (BANDS - 1)) == (BANDS - 1));
    }
    __syncthreads();

    if (lastflag && t < STEPS) {
        unsigned v = __hip_atomic_load(&acc[img * STEPS + t],
                                       __ATOMIC_ACQUIRE,
                                       __HIP_MEMORY_SCOPE_AGENT);
        out[img * STEPS + t] = (float)(int)(v - POISON);
        // self-clean: restore poison so next launch starts from known base
        __hip_atomic_store(&acc[img * STEPS + t], POISON,
                           __ATOMIC_RELAXED, __HIP_MEMORY_SCOPE_AGENT);
        if (t == 0)
            __hip_atomic_store(&ticket[img], POISON,
                               __ATOMIC_RELAXED, __HIP_MEMORY_SCOPE_AGENT);
    }
}

extern "C" void kernel_launch(void* const* d_in, const int* in_sizes, int n_in,
                              void* d_out, int out_size, void* d_ws, size_t ws_size,
                              hipStream_t stream) {
    const float* x = (const float*)d_in[0];
    float* out = (float*)d_out;
    unsigned* acc    = (unsigned*)d_ws;        // NIMG*STEPS ints (96 KiB)
    unsigned* ticket = acc + NIMG * STEPS;     // NIMG ints

    ecc_fused<<<dim3(NIMG * BANDS), dim3(256), 0, stream>>>(x, acc, ticket, out);
}

// Round 3
// 146.329 us; speedup vs baseline: 1.9248x; 1.9248x over previous
//
#include <hip/hip_runtime.h>

// R9: exact revert to the R0/R6 two-kernel structure (best verified: 145.2us).
// R7 lesson: ROWS_PW=16 crosses the 128-VGPR occupancy cliff (+6us).
// R8 lesson: fused single-kernel with AGENT-scope acq/rel atomics collapses
// codegen (VGPR 96->32, spills/load-sinking) AND forces per-block L2
// invalidate/writeback on the non-coherent 8-XCD hierarchy: kernel 22->178us.
// Plain stores + a second tiny kernel is the right structure on this HW.

#define IMG     256
#define NIMG    384                    // B*C = 128*3
#define STEPS   64
#define ROWS_PW 8                      // rows per wave
#define WAVES   4
#define ROWS_PB (ROWS_PW * WAVES)      // 32 rows per block
#define BANDS   (IMG / ROWS_PB)        // 8 blocks per image -> 3072 blocks
#define NROWS   (ROWS_PW + 2)          // rows held in registers (with halo)
#define INFV    1e30f

// bin = clip(ceil((v-0.02)/RES), 0, 63); fused form ceil(v*65.625 - 1.3125).
// Differs from the reference's f32 divide only on ~ULP bin-boundary values;
// absmax tolerance absorbs that.
__device__ __forceinline__ int bin_of(float v) {
    int t = (int)ceilf(__builtin_fmaf(v, 65.625f, -1.3125f));
    t = t < 0 ? 0 : t;
    return t > 63 ? 63 : t;
}

// Max-vertex attribution: each cell (vertex/edge/square) is attributed to its
// (value, index)-max corner; all cells owned by a pixel share its filtration
// -> one integer LDS-histogram add per pixel.
// R5 lesson: ALL row loads issued back-to-back (single vmcnt drain per wave).
// R6 lessons: inlined per-row halo shuffles (lower VGPR); every cell-pair
// float compare computed ONCE and reused complemented (a<=b == !(b<a)).
__global__ __launch_bounds__(256) void ecc_main(const float* __restrict__ x,
                                                int* __restrict__ hist) {
    const int img  = blockIdx.x / BANDS;
    const int band = blockIdx.x % BANDS;
    const int lane = threadIdx.x & 63;
    const int wave = threadIdx.x >> 6;
    const int col0 = lane * 4;
    const int r0   = band * ROWS_PB + wave * ROWS_PW;

    __shared__ int lh[WAVES][STEPS];           // per-wave sub-histograms
    ((int*)lh)[threadIdx.x] = 0;               // 4*64 == 256
    __syncthreads();

    const float* base = x + (size_t)img * (IMG * IMG);

    // Stage 1: all row loads back-to-back (wave's 64 lanes x 4 cols = one
    // full 256-wide row -> exactly 1 VMEM instruction per row).
    float4 q[NROWS];
#pragma unroll
    for (int k = 0; k < NROWS; ++k) {
        int r = r0 - 1 + k;                    // wave-uniform bounds test
        if ((unsigned)r < IMG) q[k] = *(const float4*)(base + r * IMG + col0);
        else                   q[k] = make_float4(INFV, INFV, INFV, INFV);
    }

    auto halo = [&](int k, float& l, float& r) {
        float lv = __shfl_up(q[k].w, 1, 64);   // lane-1's last element
        float rv = __shfl_down(q[k].x, 1, 64); // lane+1's first element
        l = (lane == 0)  ? INFV : lv;          // lane 0 = image col 0
        r = (lane == 63) ? INFV : rv;          // lane 63 ends at col 255
    };

    // Carried up-row flags (window cols 1..4): pU[i]=(u[i]<=c[i]),
    // pUR[i]=(u[i+1]<=c[i]), pUL[i]=(u[i-1]<=c[i]).
    bool pU[5], pUR[5], pUL[5];
    float chl, chr;                            // halos of current c row
    {
        float uhl, uhr;
        halo(0, uhl, uhr);
        halo(1, chl, chr);
        float u[6] = {uhl, q[0].x, q[0].y, q[0].z, q[0].w, uhr};
        float c[6] = {chl, q[1].x, q[1].y, q[1].z, q[1].w, chr};
#pragma unroll
        for (int i = 1; i <= 4; ++i) {
            pU[i]  = (u[i]     <= c[i]);
            pUR[i] = (u[i + 1] <= c[i]);
            pUL[i] = (u[i - 1] <= c[i]);
        }
    }

#pragma unroll
    for (int k = 1; k <= ROWS_PW; ++k) {
        float dhl, dhr;
        halo(k + 1, dhl, dhr);
        float c[6] = {chl, q[k].x,     q[k].y,     q[k].z,     q[k].w,     chr};
        float d[6] = {dhl, q[k + 1].x, q[k + 1].y, q[k + 1].z, q[k + 1].w, dhr};

        bool eD[5], dDR[5], dDL[5], eR[5];
#pragma unroll
        for (int i = 1; i <= 4; ++i) {
            eD[i]  = (d[i]     < c[i]);        // p owns down edge
            dDR[i] = (d[i + 1] < c[i]);        // down-right diagonal compare
            dDL[i] = (d[i - 1] < c[i]);        // down-left  diagonal compare
            eR[i]  = (c[i + 1] < c[i]);        // p owns right edge
        }
        bool dDRm = (d[1] < c[0]);             // serves next row's pUL[1]
        bool dDLp = (d[4] < c[5]);             // serves next row's pUR[4]
        bool oLn  = (c[0] <= c[1]);            // oL for i=1

#pragma unroll
        for (int i = 1; i <= 4; ++i) {
            float cv = c[i];
            bool oR = eR[i], oL = oLn, oD = eD[i], oU = pU[i];
            bool sDR = oR & oD & dDR[i];
            bool sDL = oL & oD & dDL[i];
            bool sUR = oU & oR & pUR[i];
            bool sUL = oU & oL & pUL[i];
            int contrib = 1 - ((int)oR + (int)oL + (int)oD + (int)oU)
                            + ((int)sDR + (int)sDL + (int)sUR + (int)sUL);
            if (cv <= 0.98f && contrib)        // reference T_MAX mask
                atomicAdd(&lh[wave][bin_of(cv)], contrib);
            oLn = !eR[i];                      // oL(i+1) = !(c[i+1] < c[i])
        }

        // rotate: current down-compares become next row's up-flags (negated)
#pragma unroll
        for (int i = 1; i <= 4; ++i) pU[i] = !eD[i];
        pUR[1] = !dDL[2]; pUR[2] = !dDL[3]; pUR[3] = !dDL[4]; pUR[4] = !dDLp;
        pUL[1] = !dDRm;   pUL[2] = !dDR[1]; pUL[3] = !dDR[2]; pUL[4] = !dDR[3];
        chl = dhl; chr = dhr;
    }

    __syncthreads();
    if (threadIdx.x < STEPS) {
        int t = threadIdx.x;
        // plain store to this block's private slot (d_ws is 0xAA-poisoned,
        // so write unconditionally, zeros included)
        hist[blockIdx.x * STEPS + t] = lh[0][t] + lh[1][t] + lh[2][t] + lh[3][t];
    }
}

// One wave64 per image: sum its 8 band histograms, inclusive shfl scan, f32 out.
__global__ __launch_bounds__(64) void ecc_scan(const int* __restrict__ hist,
                                               float* __restrict__ out) {
    const int img = blockIdx.x;
    const int t   = threadIdx.x;
    int v = 0;
#pragma unroll
    for (int b = 0; b < BANDS; ++b)
        v += hist[(img * BANDS + b) * STEPS + t];
#pragma unroll
    for (int s = 1; s < 64; s <<= 1) {
        int y = __shfl_up(v, s, 64);
        if (t >= s) v += y;
    }
    out[img * STEPS + t] = (float)v;
}

extern "C" void kernel_launch(void* const* d_in, const int* in_sizes, int n_in,
                              void* d_out, int out_size, void* d_ws, size_t ws_size,
                              hipStream_t stream) {
    const float* x = (const float*)d_in[0];
    float* out = (float*)d_out;
    int* hist = (int*)d_ws;                    // NIMG*BANDS*STEPS ints (768 KiB)

    ecc_main<<<dim3(NIMG * BANDS), dim3(256), 0, stream>>>(x, hist);
    ecc_scan<<<dim3(NIMG), dim3(64), 0, stream>>>(hist, out);
}